// Round 11
// baseline (5309.113 us; speedup 1.0000x reference)
//
#include <hip/hip_runtime.h>

#define HID   512
#define BATCH 256
#define SEQ   512
#define NBLK  192
#define NTHR  512
#define HARR2 131072   // halves per (layer,parity): [bt(4)][ks(32)][ko(2)][m(64)][j(8)]

typedef __attribute__((ext_vector_type(8))) _Float16 half8;
typedef __attribute__((ext_vector_type(4))) float f32x4;
typedef __attribute__((ext_vector_type(16))) float f32x16;

typedef __attribute__((address_space(1))) const unsigned int kGlobU32;
typedef __attribute__((address_space(3))) unsigned int kLdsU32;

__device__ __forceinline__ float sigf(float x) {
  return __builtin_amdgcn_rcpf(1.0f + __expf(-x));
}
__device__ __forceinline__ float tanhf_(float x) {
  return 1.0f - 2.0f * __builtin_amdgcn_rcpf(__expf(2.0f * x) + 1.0f);
}

__device__ __forceinline__ half8 cvt8(const float* p) {
  const float4 a = ((const float4*)p)[0];
  const float4 b = ((const float4*)p)[1];
  half8 r;
  r[0] = (_Float16)a.x; r[1] = (_Float16)a.y; r[2] = (_Float16)a.z; r[3] = (_Float16)a.w;
  r[4] = (_Float16)b.x; r[5] = (_Float16)b.y; r[6] = (_Float16)b.z; r[7] = (_Float16)b.w;
  return r;
}

// system-scope coalesced 8B store (write-through LLC; no wbL2 fence needed)
__device__ __forceinline__ void store_sys8(_Float16* p, unsigned long long v) {
  asm volatile("global_store_dwordx2 %0, %1, off sc0 sc1" :: "v"(p), "v"(v) : "memory");
}

// stage a 64 KiB A-tile (linear fragment-major copy); aux=17: read at LLC, bypass stale L2
#define STAGE(SRC, BUFB) do { \
  _Pragma("unroll") \
  for (int q = 0; q < 8; ++q) { \
    const int jj = wave * 8 + q; \
    const _Float16* gsrc = (SRC) + bt * 32768 + jj * 512 + lane * 8; \
    __builtin_amdgcn_global_load_lds((kGlobU32*)gsrc, \
        (kLdsU32*)(sA + (BUFB) * 32768 + jj * 512), 16, 0, 17); \
  } } while (0)

// one GEMM pass over a staged tile: 16 K-steps (this wave's K-half) x 2 row-tiles.
// A-frag: lane reads A[row = l31 (+32)][k = ks*16 + hi2*8 + j] from slab jj=(ks)*2+hi2
#define MFMA_PASS(WARR, BUFB) do { \
  _Pragma("unroll") \
  for (int ks = 0; ks < 16; ++ks) { \
    const int jj = (hk0 + ks) * 2 + hi2; \
    const half8 av0 = *(const half8*)(sA + (BUFB) * 32768 + jj * 512 + l31 * 8); \
    const half8 av1 = *(const half8*)(sA + (BUFB) * 32768 + jj * 512 + 256 + l31 * 8); \
    a0 = __builtin_amdgcn_mfma_f32_32x32x16_f16(av0, WARR[ks], a0, 0, 0, 0); \
    a1 = __builtin_amdgcn_mfma_f32_32x32x16_f16(av1, WARR[ks], a1, 0, 0, 0); \
  } } while (0)

#define VMCNT8 asm volatile("s_waitcnt vmcnt(8)" ::: "memory")
#define VMCNT0 asm volatile("s_waitcnt vmcnt(0)" ::: "memory")
#define SBAR() __builtin_amdgcn_s_barrier()

__device__ __forceinline__ void poll_ge(int* p, int v) {
  while (__hip_atomic_load(p, __ATOMIC_RELAXED, __HIP_MEMORY_SCOPE_AGENT) < v)
    __builtin_amdgcn_s_sleep(1);
}

__global__ __launch_bounds__(NTHR, 2)   // 8 waves = 2/SIMD -> 256-reg unified cap
void lstm3_persistent(const float* __restrict__ tracks,
                      const float* __restrict__ Wih0, const float* __restrict__ bih0,
                      const float* __restrict__ Whh0, const float* __restrict__ bhh0,
                      const float* __restrict__ Wih1, const float* __restrict__ bih1,
                      const float* __restrict__ Whh1, const float* __restrict__ bhh1,
                      const float* __restrict__ Wih2, const float* __restrict__ bih2,
                      const float* __restrict__ Whh2, const float* __restrict__ bhh2,
                      const float* __restrict__ Wpred, const float* __restrict__ bpred,
                      float* __restrict__ out, unsigned short* __restrict__ ws,
                      int* __restrict__ prog)
{
  extern __shared__ _Float16 sA[];      // 2 x 64 KiB A-staging buffers (dynamic)
  __shared__ _Float16 sB[2048];         // 4 KiB h-store bounce (dest-linear)

  const int blk  = blockIdx.x;
  const int bt   = (blk >> 1) & 3;            // batch tile (64 rows); XCD-pair local
  const int rr   = (blk & 1) * 24 + (blk >> 3);  // 0..47
  const int layer = rr >> 4;                  // 0,1,2
  const int ug    = rr & 15;                  // unit group (32 units)
  const int u0    = ug * 32;
  const int tid  = threadIdx.x;
  const int lane = tid & 63;
  const int wave = tid >> 6;
  const int l31  = lane & 31;
  const int hi2  = lane >> 5;                 // k-octet within a K=16 step
  const int cg   = wave >> 1;                 // gate-col group (32 cols)
  const int h    = wave & 1;                  // K-half (256 each)
  const int hk0  = h * 16;                    // first K-step of this wave's half
  const int h32  = h * 32;                    // owned row-tile offset after reduction
  const int gc   = cg * 32 + l31;             // block-local gate col 0..127
  const int unit_rel = gc >> 2;               // unit within block 0..31
  const int tg   = gc & 3;                    // gate type i,f,g,o
  const int unit = u0 + unit_rel;
  const int grow = tg * HID + unit;           // global gate row
  const int krel = unit_rel;                  // K index of h (for producer store)

  const float* Wih = (layer == 0) ? Wih0 : (layer == 1 ? Wih1 : Wih2);
  const float* Whh = (layer == 0) ? Whh0 : (layer == 1 ? Whh1 : Whh2);
  const float* bih = (layer == 0) ? bih0 : (layer == 1 ? bih1 : bih2);
  const float* bhh = (layer == 0) ? bhh0 : (layer == 1 ? bhh1 : bhh2);

  // ---- weights into registers/AGPRs: 32 cols x 256-K-half per wave = 64 regs/matrix ----
  half8 whh_r[16], wih_r[16];
  #pragma unroll
  for (int ks = 0; ks < 16; ++ks) {
    const int col = h * 256 + ks * 16 + hi2 * 8;
    whh_r[ks] = cvt8(Whh + (size_t)grow * 512 + col);
    if (layer > 0) wih_r[ks] = cvt8(Wih + (size_t)grow * 512 + col);
    else { half8 z = {}; wih_r[ks] = z; }
  }

  const float bias_c = bih[grow] + bhh[grow];
  float w0_c = 0.f, w1_c = 0.f;
  if (layer == 0) { w0_c = Wih0[grow * 2]; w1_c = Wih0[grow * 2 + 1]; }

  float cst[16];
  #pragma unroll
  for (int r = 0; r < 16; ++r) cst[r] = 0.f;

  _Float16* hws = (_Float16*)ws;              // 6 arrays of HARR2 halves
  const int sb = (lane & 32) | (l31 & 28);    // shuffle base: 4 gates of my unit
  const int myflag   = (layer * 4 + bt) * 32;
  const int prodflag = ((layer - 1) * 4 + bt) * 32;
  const int consflag = ((layer + 1) * 4 + bt) * 32;

  for (int t = 0; t < SEQ; ++t) {
    const int pr = (t + 1) & 1;
    const int pw = t & 1;

    // layer-0 input loads hoisted above the poll: off the critical path
    float2 xv[16];
    if (layer == 0) {
      #pragma unroll
      for (int r = 0; r < 16; ++r) {
        const int m = bt * 64 + (r & 3) + 8 * (r >> 2) + 4 * hi2 + h32;
        xv[r] = ((const float2*)tracks)[(size_t)m * SEQ + t];
      }
    }

    // ---- distributed sync: 3 conditions polled by 3 waves in parallel (R10-proven) ----
    if (tid == 0) {
      if (layer > 0) poll_ge(&prog[prodflag], 16 * (t + 1));
    } else if (tid == 64) {
      if (t > 0) poll_ge(&prog[myflag], 16 * t);
    } else if (tid == 128) {
      if (layer < 2 && t >= 2) poll_ge(&prog[consflag], 16 * (t - 1));
    }
    __syncthreads();

    const bool doH = (t > 0);
    const bool doX = (layer > 0);
    const _Float16* Hs = hws + (size_t)(layer * 2 + pr) * HARR2;
    const _Float16* Xs = doX ? hws + (size_t)((layer - 1) * 2 + pw) * HARR2 : (const _Float16*)0;

    f32x16 a0, a1;   // K-partial accumulators for row-tiles 0 (rows 0-31) and 1 (32-63)
    #pragma unroll
    for (int j = 0; j < 16; ++j) { a0[j] = 0.f; a1[j] = 0.f; }

    // ---- single stage phase: both tiles resident; X-loads overlap H-GEMM ----
    if (doH) STAGE(Hs, 0);
    if (doX) STAGE(Xs, 1);
    if (doH && doX) {
      VMCNT8; SBAR();             // all waves' H-tile complete
      MFMA_PASS(whh_r, 0);
      VMCNT0; SBAR();             // all waves' X-tile complete
      MFMA_PASS(wih_r, 1);
    } else if (doH) {
      VMCNT0; SBAR();
      MFMA_PASS(whh_r, 0);
    } else if (doX) {
      VMCNT0; SBAR();
      MFMA_PASS(wih_r, 1);
    }

    // ---- cross-wave K-reduction: wave pair (cg,0)/(cg,1); each finishes one row-tile ----
    __syncthreads();                       // all tile reads done; sA front 32 KB free
    {
      float* xch = (float*)sA;             // [q(4)][wave(8)][lane(64)] float4: conflict-free
      #pragma unroll
      for (int q = 0; q < 4; ++q) {
        f32x4 v;
        if (h == 0) { v[0]=a1[q*4]; v[1]=a1[q*4+1]; v[2]=a1[q*4+2]; v[3]=a1[q*4+3]; }
        else        { v[0]=a0[q*4]; v[1]=a0[q*4+1]; v[2]=a0[q*4+2]; v[3]=a0[q*4+3]; }
        *(f32x4*)(xch + q * 2048 + wave * 256 + lane * 4) = v;
      }
    }
    __syncthreads();
    f32x16 accO;                           // completed accumulator for owned row-tile
    {
      float* xch = (float*)sA;
      if (h == 0) accO = a0; else accO = a1;
      #pragma unroll
      for (int q = 0; q < 4; ++q) {
        const f32x4 v = *(const f32x4*)(xch + q * 2048 + (wave ^ 1) * 256 + lane * 4);
        accO[q*4]   += v[0];
        accO[q*4+1] += v[1];
        accO[q*4+2] += v[2];
        accO[q*4+3] += v[3];
      }
    }

    // ---- elementwise; h written to LDS bounce in dest-linear order ----
    #pragma unroll
    for (int r = 0; r < 16; ++r) {
      float g = accO[r] + bias_c;
      if (layer == 0) g += w0_c * xv[r].x + w1_c * xv[r].y;
      const float gi_ = __shfl(g, sb | 0, 64);
      const float gf_ = __shfl(g, sb | 1, 64);
      const float gg_ = __shfl(g, sb | 2, 64);
      const float go_ = __shfl(g, sb | 3, 64);
      const float iv = sigf(gi_);
      const float fv = sigf(gf_);
      const float gn = tanhf_(gg_);
      const float ov = sigf(go_);
      const float cn = fv * cst[r] + iv * gn;
      cst[r] = cn;
      const float hn = ov * tanhf_(cn);
      if (tg == 0) {   // one gate-group writes h for its unit
        const int m = (r & 3) + 8 * (r >> 2) + 4 * hi2 + h32;   // row 0..63
        sB[(krel >> 4) * 1024 + ((krel >> 3) & 1) * 512 + m * 8 + (krel & 7)] = (_Float16)hn;
      }
    }

    // ---- coalesced system-scope store of the contiguous 4 KiB h-block (R10 publish) ----
    __syncthreads();   // bounce visible
    {
      _Float16* wr = hws + (size_t)(layer * 2 + pw) * HARR2;
      const unsigned long long v = *(const unsigned long long*)(sB + tid * 4);
      store_sys8(wr + bt * 32768 + ug * 2048 + tid * 4, v);
    }
    VMCNT0;            // own stores at LLC
    __syncthreads();   // all waves' stores at LLC
    if (tid == 0)
      __hip_atomic_fetch_add(&prog[myflag], 1, __ATOMIC_RELAXED,
                             __HIP_MEMORY_SCOPE_AGENT);
  }

  // ---- final sync: all layer-2 groups at 512; acquire for normal-load epilogue ----
  if (tid == 0) {
    #pragma unroll
    for (int b = 0; b < 4; ++b) poll_ge(&prog[(8 + b) * 32], 16 * SEQ);
    __builtin_amdgcn_fence(__ATOMIC_ACQUIRE, "agent");
  }
  __syncthreads();

  // ---- output head: out[b][p] = elu(h2_final[b]) . Wpred[p] + bpred[p] ----
  const int gw = blk * 8 + wave;
  if (gw < BATCH * 4) {
    const int b = gw >> 2;
    const int p = gw & 3;
    const _Float16* Hf = hws + (size_t)5 * HARR2;   // layer 2, parity 1 (t=511)
    // k = lane*8: addr = [bt=b>>6]*32768 + (lane>>1)*1024 + (lane&1)*512 + (b&63)*8
    const half8 hh = *(const half8*)(Hf + (size_t)(b >> 6) * 32768 + lane * 512 + (b & 63) * 8);
    float a = 0.f;
    #pragma unroll
    for (int j = 0; j < 8; ++j) {
      const float hv = (float)hh[j];
      const float e = hv > 0.f ? hv : expm1f(hv);
      a += e * Wpred[p * HID + lane * 8 + j];
    }
    #pragma unroll
    for (int off = 32; off > 0; off >>= 1) a += __shfl_down(a, off, 64);
    if (lane == 0) out[b * 4 + p] = a + bpred[p];
  }
}

extern "C" void kernel_launch(void* const* d_in, const int* in_sizes, int n_in,
                              void* d_out, int out_size, void* d_ws, size_t ws_size,
                              hipStream_t stream) {
  const float* tracks = (const float*)d_in[0];
  const float* Wih0  = (const float*)d_in[1];
  const float* bih0  = (const float*)d_in[2];
  const float* Whh0  = (const float*)d_in[3];
  const float* bhh0  = (const float*)d_in[4];
  const float* Wih1  = (const float*)d_in[5];
  const float* bih1  = (const float*)d_in[6];
  const float* Whh1  = (const float*)d_in[7];
  const float* bhh1  = (const float*)d_in[8];
  const float* Wih2  = (const float*)d_in[9];
  const float* bih2  = (const float*)d_in[10];
  const float* Whh2  = (const float*)d_in[11];
  const float* bhh2  = (const float*)d_in[12];
  const float* Wpred = (const float*)d_in[13];
  const float* bpred = (const float*)d_in[14];
  float* out = (float*)d_out;
  unsigned short* ws = (unsigned short*)d_ws;
  int* prog = (int*)((char*)d_ws + (size_t)6 * HARR2 * 2);   // 12 padded counters

  hipFuncSetAttribute(reinterpret_cast<const void*>(lstm3_persistent),
                      hipFuncAttributeMaxDynamicSharedMemorySize, 131072);

  // zero only the progress counters (h needs no init: t=0 skips the hidden pass)
  hipMemsetAsync(prog, 0, 12 * 32 * sizeof(int), stream);

  void* args[] = { &tracks, &Wih0, &bih0, &Whh0, &bhh0,
                   &Wih1, &bih1, &Whh1, &bhh1,
                   &Wih2, &bih2, &Whh2, &bhh2,
                   &Wpred, &bpred, &out, &ws, &prog };
  hipLaunchCooperativeKernel(reinterpret_cast<void*>(lstm3_persistent),
                             dim3(NBLK), dim3(NTHR), args, 131072, stream);
}

// Round 12
// 4487.440 us; speedup vs baseline: 1.1831x; 1.1831x over previous
//
#include <hip/hip_runtime.h>

#define HID   512
#define BATCH 256
#define SEQ   512
#define NBLK  192
#define NTHR  512
#define HARR2 131072   // halves per (layer,parity): [16ug][16 bt*4+rt][4ko][16row][8j]

typedef __attribute__((ext_vector_type(8))) _Float16 half8;
typedef __attribute__((ext_vector_type(4))) float f32x4;

typedef __attribute__((address_space(1))) const unsigned int kGlobU32;
typedef __attribute__((address_space(3))) unsigned int kLdsU32;

__device__ __forceinline__ float sigf(float x) {
  return __builtin_amdgcn_rcpf(1.0f + __expf(-x));
}
__device__ __forceinline__ float tanhf_(float x) {
  return 1.0f - 2.0f * __builtin_amdgcn_rcpf(__expf(2.0f * x) + 1.0f);
}

__device__ __forceinline__ half8 cvt8(const float* p) {
  const float4 a = ((const float4*)p)[0];
  const float4 b = ((const float4*)p)[1];
  half8 r;
  r[0] = (_Float16)a.x; r[1] = (_Float16)a.y; r[2] = (_Float16)a.z; r[3] = (_Float16)a.w;
  r[4] = (_Float16)b.x; r[5] = (_Float16)b.y; r[6] = (_Float16)b.z; r[7] = (_Float16)b.w;
  return r;
}

// system-scope coalesced 8B store (write-through LLC; no wbL2 fence needed)
__device__ __forceinline__ void store_sys8(_Float16* p, unsigned long long v) {
  asm volatile("global_store_dwordx2 %0, %1, off sc0 sc1" :: "v"(p), "v"(v) : "memory");
}

// stage a 64 KiB A-tile into LDS buffer BUFB; aux=17 (sc0|sc1): read at LLC, bypass stale L2
#define STAGE(SRC, BUFB) do { \
  _Pragma("unroll") \
  for (int q = 0; q < 8; ++q) { \
    const int s = wave * 8 + q; \
    const _Float16* gsrc = (SRC) + ((s >> 2) * 16 + bt * 4 + (s & 3)) * 512 + lane * 8; \
    __builtin_amdgcn_global_load_lds((kGlobU32*)gsrc, \
        (kLdsU32*)(sA + (BUFB) * 32768 + s * 512), 16, 0, 17); \
  } } while (0)

// one GEMM pass over a staged A-tile: 16 k-steps x 4 row-tiles, B from registers
#define MFMA_PASS(WARR, BUFB) do { \
  _Pragma("unroll") \
  for (int ks = 0; ks < 16; ++ks) { \
    _Pragma("unroll") \
    for (int rt = 0; rt < 4; ++rt) { \
      const half8 av = *(const half8*)(sA + (BUFB) * 32768 + (ks * 4 + rt) * 512 + lane * 8); \
      acc[rt] = __builtin_amdgcn_mfma_f32_16x16x32_f16(av, WARR[ks], acc[rt], 0, 0, 0); \
    } } } while (0)

#define VMCNT8 asm volatile("s_waitcnt vmcnt(8)" ::: "memory")
#define VMCNT0 asm volatile("s_waitcnt vmcnt(0)" ::: "memory")
#define SBAR() __builtin_amdgcn_s_barrier()

__device__ __forceinline__ void poll_ge(int* p, int v) {
  while (__hip_atomic_load(p, __ATOMIC_RELAXED, __HIP_MEMORY_SCOPE_AGENT) < v)
    __builtin_amdgcn_s_sleep(1);
}

__global__ __launch_bounds__(NTHR, 2)   // 8 waves = 2/SIMD -> 256-VGPR cap
void lstm3_persistent(const float* __restrict__ tracks,
                      const float* __restrict__ Wih0, const float* __restrict__ bih0,
                      const float* __restrict__ Whh0, const float* __restrict__ bhh0,
                      const float* __restrict__ Wih1, const float* __restrict__ bih1,
                      const float* __restrict__ Whh1, const float* __restrict__ bhh1,
                      const float* __restrict__ Wih2, const float* __restrict__ bih2,
                      const float* __restrict__ Whh2, const float* __restrict__ bhh2,
                      const float* __restrict__ Wpred, const float* __restrict__ bpred,
                      float* __restrict__ out, unsigned short* __restrict__ ws,
                      int* __restrict__ prog)
{
  extern __shared__ _Float16 sA[];      // 2 x 64 KiB A-staging buffers (dynamic)
  __shared__ _Float16 sB[2048];         // 4 KiB h-store bounce

  const int blk  = blockIdx.x;
  const int bt   = (blk >> 1) & 3;            // batch tile (64 rows); XCD-pair local
  const int rr   = (blk & 1) * 24 + (blk >> 3);  // 0..47
  const int layer = rr >> 4;                  // 0,1,2
  const int ug    = rr & 15;                  // unit group (32 units)
  const int u0    = ug * 32;
  const int tid  = threadIdx.x;
  const int lane = tid & 63;
  const int wave = tid >> 6;
  const int c    = lane & 15;                 // gate col within wave
  const int kod  = lane >> 4;                 // k-octet / D-row group
  const int tg   = c & 3;                     // gate type i,f,g,o
  const int usub = c >> 2;
  const int unit = u0 + wave * 4 + usub;      // this lane's hidden unit
  const int grow = tg * HID + unit;           // global gate row

  const float* Wih = (layer == 0) ? Wih0 : (layer == 1 ? Wih1 : Wih2);
  const float* Whh = (layer == 0) ? Whh0 : (layer == 1 ? Whh1 : Whh2);
  const float* bih = (layer == 0) ? bih0 : (layer == 1 ? bih1 : bih2);
  const float* bhh = (layer == 0) ? bhh0 : (layer == 1 ? bhh1 : bhh2);

  // ---- weights into registers/AGPRs: 16 cols/wave -> 64 regs per matrix ----
  half8 whh_r[16], wih_r[16];
  #pragma unroll
  for (int ks = 0; ks < 16; ++ks) {
    const int col = ks * 32 + kod * 8;
    whh_r[ks] = cvt8(Whh + (size_t)grow * 512 + col);
    if (layer > 0) wih_r[ks] = cvt8(Wih + (size_t)grow * 512 + col);
    else { half8 z = {}; wih_r[ks] = z; }
  }

  const float bias_c = bih[grow] + bhh[grow];
  float w0_c = 0.f, w1_c = 0.f;
  if (layer == 0) { w0_c = Wih0[grow * 2]; w1_c = Wih0[grow * 2 + 1]; }

  float cst[16];
  #pragma unroll
  for (int r = 0; r < 16; ++r) cst[r] = 0.f;

  _Float16* hws = (_Float16*)ws;              // 6 arrays of HARR2 halves
  const int sb = (lane & 48) | (c & 12);      // shuffle base: 4 gates of my unit-slot
  const int myflag   = (layer * 4 + bt) * 32;
  const int prodflag = ((layer - 1) * 4 + bt) * 32;
  const int consflag = ((layer + 1) * 4 + bt) * 32;
  const int st_rt = tid >> 7;
  const int st_wi = (tid * 4) & 511;

  for (int t = 0; t < SEQ; ++t) {
    const int pr = (t + 1) & 1;
    const int pw = t & 1;

    // ---- distributed sync: 3 conditions, 3 waves, no fences ----
    if (tid == 0) {
      if (layer > 0) poll_ge(&prog[prodflag], 16 * (t + 1));
    } else if (tid == 64) {
      if (t > 0) poll_ge(&prog[myflag], 16 * t);
    } else if (tid == 128) {
      if (layer < 2 && t >= 2) poll_ge(&prog[consflag], 16 * (t - 1));
    }
    __syncthreads();

    const bool doH = (t > 0);
    const bool doX = (layer > 0);
    const _Float16* Hs = hws + (size_t)(layer * 2 + pr) * HARR2;
    const _Float16* Xs = doX ? hws + (size_t)((layer - 1) * 2 + pw) * HARR2 : (const _Float16*)0;

    f32x4 acc[4];
    #pragma unroll
    for (int rt = 0; rt < 4; ++rt) { acc[rt][0]=0.f; acc[rt][1]=0.f; acc[rt][2]=0.f; acc[rt][3]=0.f; }

    // ---- single stage phase: both tiles resident; X-loads overlap H-GEMM ----
    if (doH) STAGE(Hs, 0);
    if (doX) STAGE(Xs, 1);
    if (doH && doX) {
      VMCNT8; SBAR();             // all waves' H-tile complete
      MFMA_PASS(whh_r, 0);
      VMCNT0; SBAR();             // all waves' X-tile complete
      MFMA_PASS(wih_r, 1);
    } else if (doH) {
      VMCNT0; SBAR();
      MFMA_PASS(whh_r, 0);
    } else if (doX) {
      VMCNT0; SBAR();
      MFMA_PASS(wih_r, 1);
    }

    // ---- elementwise; h written to LDS bounce ----
    #pragma unroll
    for (int rt = 0; rt < 4; ++rt) {
      float2 xv[4];
      if (layer == 0) {
        #pragma unroll
        for (int rg = 0; rg < 4; ++rg) {
          const int m = bt * 64 + rt * 16 + kod * 4 + rg;
          xv[rg] = ((const float2*)tracks)[(size_t)m * SEQ + t];
        }
      }
      #pragma unroll
      for (int rg = 0; rg < 4; ++rg) {
        float g = acc[rt][rg] + bias_c;
        if (layer == 0) g += w0_c * xv[rg].x + w1_c * xv[rg].y;
        const float gi_ = __shfl(g, sb | 0, 64);
        const float gf_ = __shfl(g, sb | 1, 64);
        const float gg_ = __shfl(g, sb | 2, 64);
        const float go_ = __shfl(g, sb | 3, 64);
        const float iv = sigf(gi_);
        const float fv = sigf(gf_);
        const float gn = tanhf_(gg_);
        const float ov = sigf(go_);
        const float cn = fv * cst[rt * 4 + rg] + iv * gn;
        cst[rt * 4 + rg] = cn;
        const float hn = ov * tanhf_(cn);
        if (tg == 0) {   // one gate-group writes h for its unit -> LDS bounce
          const int r16 = kod * 4 + rg;
          sB[rt * 512 + ((unit >> 3) & 3) * 128 + r16 * 8 + (unit & 7)] = (_Float16)hn;
        }
      }
    }

    // ---- coalesced system-scope store of the 4 KiB h-tile ----
    __syncthreads();   // bounce visible
    {
      _Float16* wr = hws + (size_t)(layer * 2 + pw) * HARR2;
      const unsigned long long v = *(const unsigned long long*)(sB + tid * 4);
      store_sys8(wr + ((size_t)(ug * 16 + bt * 4 + st_rt) << 9) + st_wi, v);
    }
    VMCNT0;            // own stores at LLC
    __syncthreads();   // all waves' stores at LLC
    if (tid == 0)
      __hip_atomic_fetch_add(&prog[myflag], 1, __ATOMIC_RELAXED,
                             __HIP_MEMORY_SCOPE_AGENT);
  }

  // ---- final sync: all layer-2 groups at 512; acquire for normal-load epilogue ----
  if (tid == 0) {
    #pragma unroll
    for (int b = 0; b < 4; ++b) poll_ge(&prog[(8 + b) * 32], 16 * SEQ);
    __builtin_amdgcn_fence(__ATOMIC_ACQUIRE, "agent");
  }
  __syncthreads();

  // ---- output head: out[b][p] = elu(h2_final[b]) . Wpred[p] + bpred[p] ----
  const int gw = blk * 8 + wave;
  if (gw < BATCH * 4) {
    const int b = gw >> 2;
    const int p = gw & 3;
    const _Float16* Hf = hws + (size_t)5 * HARR2;   // layer 2, parity 1 (t=511)
    const size_t base = ((size_t)((lane >> 2) * 16 + (b >> 4)) * 4 + (lane & 3)) * 128
                        + (size_t)(b & 15) * 8;
    const half8 hh = *(const half8*)(Hf + base);
    float a = 0.f;
    #pragma unroll
    for (int j = 0; j < 8; ++j) {
      const float hv = (float)hh[j];
      const float e = hv > 0.f ? hv : expm1f(hv);
      a += e * Wpred[p * HID + lane * 8 + j];
    }
    #pragma unroll
    for (int off = 32; off > 0; off >>= 1) a += __shfl_down(a, off, 64);
    if (lane == 0) out[b * 4 + p] = a + bpred[p];
  }
}

extern "C" void kernel_launch(void* const* d_in, const int* in_sizes, int n_in,
                              void* d_out, int out_size, void* d_ws, size_t ws_size,
                              hipStream_t stream) {
  const float* tracks = (const float*)d_in[0];
  const float* Wih0  = (const float*)d_in[1];
  const float* bih0  = (const float*)d_in[2];
  const float* Whh0  = (const float*)d_in[3];
  const float* bhh0  = (const float*)d_in[4];
  const float* Wih1  = (const float*)d_in[5];
  const float* bih1  = (const float*)d_in[6];
  const float* Whh1  = (const float*)d_in[7];
  const float* bhh1  = (const float*)d_in[8];
  const float* Wih2  = (const float*)d_in[9];
  const float* bih2  = (const float*)d_in[10];
  const float* Whh2  = (const float*)d_in[11];
  const float* bhh2  = (const float*)d_in[12];
  const float* Wpred = (const float*)d_in[13];
  const float* bpred = (const float*)d_in[14];
  float* out = (float*)d_out;
  unsigned short* ws = (unsigned short*)d_ws;
  int* prog = (int*)((char*)d_ws + (size_t)6 * HARR2 * 2);   // 12 padded counters

  hipFuncSetAttribute(reinterpret_cast<const void*>(lstm3_persistent),
                      hipFuncAttributeMaxDynamicSharedMemorySize, 131072);

  // zero only the progress counters (h needs no init: t=0 skips the hidden pass)
  hipMemsetAsync(prog, 0, 12 * 32 * sizeof(int), stream);

  void* args[] = { &tracks, &Wih0, &bih0, &Whh0, &bhh0,
                   &Wih1, &bih1, &Whh1, &bhh1,
                   &Wih2, &bih2, &Whh2, &bhh2,
                   &Wpred, &bpred, &out, &ws, &prog };
  hipLaunchCooperativeKernel(reinterpret_cast<void*>(lstm3_persistent),
                             dim3(NBLK), dim3(NTHR), args, 131072, stream);
}

// Round 13
// 3124.240 us; speedup vs baseline: 1.6993x; 1.4363x over previous
//
#include <hip/hip_runtime.h>

#define HID   512
#define BATCH 256
#define SEQ   512
#define NBLK  192
#define NTHR  512
#define HARR2 131072   // halves per (layer,parity): [16ug][16 bt*4+rt][4ko][16row][8j]

typedef __attribute__((ext_vector_type(8))) _Float16 half8;
typedef __attribute__((ext_vector_type(4))) float f32x4;

typedef __attribute__((address_space(1))) const unsigned int kGlobU32;
typedef __attribute__((address_space(3))) unsigned int kLdsU32;

__device__ __forceinline__ float sigf(float x) {
  return __builtin_amdgcn_rcpf(1.0f + __expf(-x));
}
__device__ __forceinline__ float tanhf_(float x) {
  return 1.0f - 2.0f * __builtin_amdgcn_rcpf(__expf(2.0f * x) + 1.0f);
}

__device__ __forceinline__ half8 cvt8(const float* p) {
  const float4 a = ((const float4*)p)[0];
  const float4 b = ((const float4*)p)[1];
  half8 r;
  r[0] = (_Float16)a.x; r[1] = (_Float16)a.y; r[2] = (_Float16)a.z; r[3] = (_Float16)a.w;
  r[4] = (_Float16)b.x; r[5] = (_Float16)b.y; r[6] = (_Float16)b.z; r[7] = (_Float16)b.w;
  return r;
}

// system-scope coalesced 8B store (write-through LLC; no wbL2 fence needed)
__device__ __forceinline__ void store_sys8(_Float16* p, unsigned long long v) {
  asm volatile("global_store_dwordx2 %0, %1, off sc0 sc1" :: "v"(p), "v"(v) : "memory");
}

// stage a 64 KiB A-tile into LDS buffer BUFB; aux=17 (sc0|sc1): read at LLC, bypass stale L2
#define STAGE(SRC, BUFB) do { \
  _Pragma("unroll") \
  for (int q = 0; q < 8; ++q) { \
    const int s = wave * 8 + q; \
    const _Float16* gsrc = (SRC) + ((s >> 2) * 16 + bt * 4 + (s & 3)) * 512 + lane * 8; \
    __builtin_amdgcn_global_load_lds((kGlobU32*)gsrc, \
        (kLdsU32*)(sA + (BUFB) * 32768 + s * 512), 16, 0, 17); \
  } } while (0)

// one GEMM pass over a staged A-tile: 16 k-steps x 4 row-tiles, B from registers
#define MFMA_PASS(WARR, BUFB) do { \
  _Pragma("unroll") \
  for (int ks = 0; ks < 16; ++ks) { \
    _Pragma("unroll") \
    for (int rt = 0; rt < 4; ++rt) { \
      const half8 av = *(const half8*)(sA + (BUFB) * 32768 + (ks * 4 + rt) * 512 + lane * 8); \
      acc[rt] = __builtin_amdgcn_mfma_f32_16x16x32_f16(av, WARR[ks], acc[rt], 0, 0, 0); \
    } } } while (0)

#define VMCNT8 asm volatile("s_waitcnt vmcnt(8)" ::: "memory")
#define VMCNT0 asm volatile("s_waitcnt vmcnt(0)" ::: "memory")
#define SBAR() __builtin_amdgcn_s_barrier()

__device__ __forceinline__ void poll_ge(int* p, int v) {
  while (__hip_atomic_load(p, __ATOMIC_RELAXED, __HIP_MEMORY_SCOPE_AGENT) < v)
    __builtin_amdgcn_s_sleep(1);
}

__global__ __launch_bounds__(NTHR, 2)   // 8 waves = 2/SIMD -> 256-VGPR cap
void lstm3_persistent(const float* __restrict__ tracks,
                      const float* __restrict__ Wih0, const float* __restrict__ bih0,
                      const float* __restrict__ Whh0, const float* __restrict__ bhh0,
                      const float* __restrict__ Wih1, const float* __restrict__ bih1,
                      const float* __restrict__ Whh1, const float* __restrict__ bhh1,
                      const float* __restrict__ Wih2, const float* __restrict__ bih2,
                      const float* __restrict__ Whh2, const float* __restrict__ bhh2,
                      const float* __restrict__ Wpred, const float* __restrict__ bpred,
                      float* __restrict__ out, unsigned short* __restrict__ ws,
                      int* __restrict__ prog)
{
  extern __shared__ _Float16 sA[];      // 2 x 64 KiB A-staging buffers (dynamic)
  __shared__ _Float16 sB[2048];         // 4 KiB h-store bounce
  __shared__ float sG[2048];            // 8 KiB gate-exchange: [wave][lane][4]

  const int blk  = blockIdx.x;
  const int bt   = (blk >> 1) & 3;            // batch tile (64 rows); XCD-pair local
  const int rr   = (blk & 1) * 24 + (blk >> 3);  // 0..47
  const int layer = rr >> 4;                  // 0,1,2
  const int ug    = rr & 15;                  // unit group (32 units)
  const int u0    = ug * 32;
  const int tid  = threadIdx.x;
  const int lane = tid & 63;
  const int wave = tid >> 6;
  const int c    = lane & 15;                 // gate col within wave
  const int kod  = lane >> 4;                 // k-octet / D-row group
  const int tg   = c & 3;                     // gate type i,f,g,o
  const int usub = c >> 2;
  const int unit = u0 + wave * 4 + usub;      // this lane's hidden unit
  const int grow = tg * HID + unit;           // global gate row

  const float* Wih = (layer == 0) ? Wih0 : (layer == 1 ? Wih1 : Wih2);
  const float* Whh = (layer == 0) ? Whh0 : (layer == 1 ? Whh1 : Whh2);
  const float* bih = (layer == 0) ? bih0 : (layer == 1 ? bih1 : bih2);
  const float* bhh = (layer == 0) ? bhh0 : (layer == 1 ? bhh1 : bhh2);

  // ---- weights into registers/AGPRs: 16 cols/wave -> 64 regs per matrix ----
  half8 whh_r[16], wih_r[16];
  #pragma unroll
  for (int ks = 0; ks < 16; ++ks) {
    const int col = ks * 32 + kod * 8;
    whh_r[ks] = cvt8(Whh + (size_t)grow * 512 + col);
    if (layer > 0) wih_r[ks] = cvt8(Wih + (size_t)grow * 512 + col);
    else { half8 z = {}; wih_r[ks] = z; }
  }

  const float bias_c = bih[grow] + bhh[grow];
  float w0_c = 0.f, w1_c = 0.f;
  if (layer == 0) { w0_c = Wih0[grow * 2]; w1_c = Wih0[grow * 2 + 1]; }

  // c-state: ONE row per rt per lane (lane-split elementwise)
  float cst[4];
  #pragma unroll
  for (int r = 0; r < 4; ++r) cst[r] = 0.f;

  _Float16* hws = (_Float16*)ws;              // 6 arrays of HARR2 halves
  const int sb = (lane & 48) | (c & 12);      // unit-quad base lane (gates at sb|0..3)
  const int myflag   = (layer * 4 + bt) * 32;
  const int prodflag = ((layer - 1) * 4 + bt) * 32;
  const int consflag = ((layer + 1) * 4 + bt) * 32;
  const int st_rt = tid >> 7;
  const int st_wi = (tid * 4) & 511;
  const int rbG = wave * 256 + sb * 4 + tg;   // gate-exchange read base

  for (int t = 0; t < SEQ; ++t) {
    const int pr = (t + 1) & 1;
    const int pw = t & 1;

    // ---- distributed sync: 3 conditions, 3 waves, no fences ----
    if (tid == 0) {
      if (layer > 0) poll_ge(&prog[prodflag], 16 * (t + 1));
    } else if (tid == 64) {
      if (t > 0) poll_ge(&prog[myflag], 16 * t);
    } else if (tid == 128) {
      if (layer < 2 && t >= 2) poll_ge(&prog[consflag], 16 * (t - 1));
    }
    __syncthreads();

    const bool doH = (t > 0);
    const bool doX = (layer > 0);
    const _Float16* Hs = hws + (size_t)(layer * 2 + pr) * HARR2;
    const _Float16* Xs = doX ? hws + (size_t)((layer - 1) * 2 + pw) * HARR2 : (const _Float16*)0;

    f32x4 acc[4];
    #pragma unroll
    for (int rt = 0; rt < 4; ++rt) { acc[rt][0]=0.f; acc[rt][1]=0.f; acc[rt][2]=0.f; acc[rt][3]=0.f; }

    // ---- single stage phase: both tiles resident; X-loads overlap H-GEMM ----
    if (doH) STAGE(Hs, 0);
    if (doX) STAGE(Xs, 1);
    if (doH && doX) {
      VMCNT8; SBAR();             // all waves' H-tile complete
      MFMA_PASS(whh_r, 0);
      VMCNT0; SBAR();             // all waves' X-tile complete
      MFMA_PASS(wih_r, 1);
    } else if (doH) {
      VMCNT0; SBAR();
      MFMA_PASS(whh_r, 0);
    } else if (doX) {
      VMCNT0; SBAR();
      MFMA_PASS(wih_r, 1);
    }

    // ---- elementwise (lane-split): LDS gate exchange; ONE row per lane per rt ----
    #pragma unroll
    for (int rt = 0; rt < 4; ++rt) {
      float2 xv[4];
      if (layer == 0) {
        #pragma unroll
        for (int rg = 0; rg < 4; ++rg) {
          const int m = bt * 64 + rt * 16 + kod * 4 + rg;
          xv[rg] = ((const float2*)tracks)[(size_t)m * SEQ + t];
        }
      }
      // publish this lane's gate column (4 rows) to the wave-private exchange
      float4 gfv;
      {
        float g0 = acc[rt][0] + bias_c, g1 = acc[rt][1] + bias_c;
        float g2 = acc[rt][2] + bias_c, g3 = acc[rt][3] + bias_c;
        if (layer == 0) {
          g0 += w0_c * xv[0].x + w1_c * xv[0].y;
          g1 += w0_c * xv[1].x + w1_c * xv[1].y;
          g2 += w0_c * xv[2].x + w1_c * xv[2].y;
          g3 += w0_c * xv[3].x + w1_c * xv[3].y;
        }
        gfv.x = g0; gfv.y = g1; gfv.z = g2; gfv.w = g3;
      }
      *(float4*)(sG + wave * 256 + lane * 4) = gfv;
      // same-wave readback (compiler inserts lgkmcnt): gates of row tg within quad
      const float gi_ = sG[rbG];        // gate i (lane sb|0)
      const float gf_ = sG[rbG + 4];    // gate f (lane sb|1)
      const float gg_ = sG[rbG + 8];    // gate g (lane sb|2)
      const float go_ = sG[rbG + 12];   // gate o (lane sb|3)
      const float iv = sigf(gi_);
      const float fv = sigf(gf_);
      const float gn = tanhf_(gg_);
      const float ov = sigf(go_);
      const float cn = fv * cst[rt] + iv * gn;
      cst[rt] = cn;
      const float hn = ov * tanhf_(cn);
      {  // every lane writes its one row for its unit
        const int r16 = kod * 4 + tg;
        sB[rt * 512 + ((unit >> 3) & 3) * 128 + r16 * 8 + (unit & 7)] = (_Float16)hn;
      }
    }

    // ---- coalesced system-scope store of the 4 KiB h-tile ----
    __syncthreads();   // bounce visible
    {
      _Float16* wr = hws + (size_t)(layer * 2 + pw) * HARR2;
      const unsigned long long v = *(const unsigned long long*)(sB + tid * 4);
      store_sys8(wr + ((size_t)(ug * 16 + bt * 4 + st_rt) << 9) + st_wi, v);
    }
    VMCNT0;            // own stores at LLC
    __syncthreads();   // all waves' stores at LLC
    if (tid == 0)
      __hip_atomic_fetch_add(&prog[myflag], 1, __ATOMIC_RELAXED,
                             __HIP_MEMORY_SCOPE_AGENT);
  }

  // ---- final sync: all layer-2 groups at 512; acquire for normal-load epilogue ----
  if (tid == 0) {
    #pragma unroll
    for (int b = 0; b < 4; ++b) poll_ge(&prog[(8 + b) * 32], 16 * SEQ);
    __builtin_amdgcn_fence(__ATOMIC_ACQUIRE, "agent");
  }
  __syncthreads();

  // ---- output head: out[b][p] = elu(h2_final[b]) . Wpred[p] + bpred[p] ----
  const int gw = blk * 8 + wave;
  if (gw < BATCH * 4) {
    const int b = gw >> 2;
    const int p = gw & 3;
    const _Float16* Hf = hws + (size_t)5 * HARR2;   // layer 2, parity 1 (t=511)
    const size_t base = ((size_t)((lane >> 2) * 16 + (b >> 4)) * 4 + (lane & 3)) * 128
                        + (size_t)(b & 15) * 8;
    const half8 hh = *(const half8*)(Hf + base);
    float a = 0.f;
    #pragma unroll
    for (int j = 0; j < 8; ++j) {
      const float hv = (float)hh[j];
      const float e = hv > 0.f ? hv : expm1f(hv);
      a += e * Wpred[p * HID + lane * 8 + j];
    }
    #pragma unroll
    for (int off = 32; off > 0; off >>= 1) a += __shfl_down(a, off, 64);
    if (lane == 0) out[b * 4 + p] = a + bpred[p];
  }
}

extern "C" void kernel_launch(void* const* d_in, const int* in_sizes, int n_in,
                              void* d_out, int out_size, void* d_ws, size_t ws_size,
                              hipStream_t stream) {
  const float* tracks = (const float*)d_in[0];
  const float* Wih0  = (const float*)d_in[1];
  const float* bih0  = (const float*)d_in[2];
  const float* Whh0  = (const float*)d_in[3];
  const float* bhh0  = (const float*)d_in[4];
  const float* Wih1  = (const float*)d_in[5];
  const float* bih1  = (const float*)d_in[6];
  const float* Whh1  = (const float*)d_in[7];
  const float* bhh1  = (const float*)d_in[8];
  const float* Wih2  = (const float*)d_in[9];
  const float* bih2  = (const float*)d_in[10];
  const float* Whh2  = (const float*)d_in[11];
  const float* bhh2  = (const float*)d_in[12];
  const float* Wpred = (const float*)d_in[13];
  const float* bpred = (const float*)d_in[14];
  float* out = (float*)d_out;
  unsigned short* ws = (unsigned short*)d_ws;
  int* prog = (int*)((char*)d_ws + (size_t)6 * HARR2 * 2);   // 12 padded counters

  hipFuncSetAttribute(reinterpret_cast<const void*>(lstm3_persistent),
                      hipFuncAttributeMaxDynamicSharedMemorySize, 131072);

  // zero only the progress counters (h needs no init: t=0 skips the hidden pass)
  hipMemsetAsync(prog, 0, 12 * 32 * sizeof(int), stream);

  void* args[] = { &tracks, &Wih0, &bih0, &Whh0, &bhh0,
                   &Wih1, &bih1, &Whh1, &bhh1,
                   &Wih2, &bih2, &Whh2, &bhh2,
                   &Wpred, &bpred, &out, &ws, &prog };
  hipLaunchCooperativeKernel(reinterpret_cast<void*>(lstm3_persistent),
                             dim3(NBLK), dim3(NTHR), args, 131072, stream);
}